// Round 11
// baseline (424.271 us; speedup 1.0000x reference)
//
#include <hip/hip_runtime.h>
#include <hip/hip_bf16.h>
#include <stdint.h>

// ---------- types ----------
typedef __attribute__((ext_vector_type(8))) __bf16 bf16x8;
typedef __attribute__((ext_vector_type(4))) float f32x4;

__device__ __forceinline__ unsigned short f2b(float f) {
    return __builtin_bit_cast(unsigned short, __float2bfloat16(f));
}

// async global -> LDS, 16B per lane (wave-uniform base + lane*16 dest order)
__device__ __forceinline__ void gload_lds16(const void* g, void* l) {
    __builtin_amdgcn_global_load_lds(
        (__attribute__((address_space(1))) void*)(uintptr_t)g,
        (__attribute__((address_space(3))) void*)l,
        16, 0, 0);
}

#define MFMA16(a, b, c) __builtin_amdgcn_mfma_f32_16x16x32_bf16((a), (b), (c), 0, 0, 0)

// ---------- constants ----------
// B=8192, S=39, A=4, D_IN=43 (pad 64), F=1024, E=8, C=10

// ---------- prep: SA pack + mixture weights ----------
__global__ void k_prep_sa(const float* __restrict__ state, const float* __restrict__ action,
                          const int* __restrict__ c, const float* __restrict__ Wte,
                          unsigned short* __restrict__ SA, float* __restrict__ wmix, int B) {
    int b = blockIdx.x * 256 + threadIdx.x;
    if (b >= B) return;
    unsigned short* row = SA + (size_t)b * 64;
#pragma unroll
    for (int i = 0; i < 39; ++i) row[i] = f2b(state[(size_t)b * 39 + i]);
#pragma unroll
    for (int i = 0; i < 4; ++i) row[39 + i] = f2b(action[(size_t)b * 4 + i]);
#pragma unroll
    for (int i = 43; i < 64; ++i) row[i] = 0;
    int ctx = c[b];
#pragma unroll
    for (int e = 0; e < 8; ++e) wmix[(size_t)b * 8 + e] = Wte[e * 10 + ctx];
}

// ---------- prep: W0 [E,43,1024] f32 -> W0T [E,1024,64] bf16 ----------
__global__ void k_prep_w0t(const float* __restrict__ W0, unsigned short* __restrict__ W0T) {
    int idx = blockIdx.x * 256 + threadIdx.x;   // e*1024 + f
    int e = idx >> 10, f = idx & 1023;
    unsigned short* dst = W0T + (size_t)idx * 64;
#pragma unroll 1
    for (int k = 0; k < 43; ++k) dst[k] = f2b(W0[((size_t)e * 43 + k) * 1024 + f]);
#pragma unroll
    for (int k = 43; k < 64; ++k) dst[k] = 0;
}

// ---------- prep: W1 [E,1024,1024] f32 -> W1T [E,1024(n),1024(k)] bf16 ----------
__global__ void k_prep_w1t(const float* __restrict__ W1, unsigned short* __restrict__ W1T) {
    __shared__ float t[64][65];
    int k0 = blockIdx.x * 64, n0 = blockIdx.y * 64, e = blockIdx.z;
    int tid = threadIdx.x;
    int cl = tid & 63, rg = tid >> 6;
    const float* src = W1 + ((size_t)e * 1024 + k0) * 1024 + n0;
#pragma unroll
    for (int i = 0; i < 16; ++i) {
        int kr = rg * 16 + i;
        t[kr][cl] = src[(size_t)kr * 1024 + cl];
    }
    __syncthreads();
    int nl = tid >> 2, kg = tid & 3;
    unsigned short* dst = W1T + ((size_t)e * 1024 + n0 + nl) * 1024 + k0 + kg * 16;
#pragma unroll
    for (int j = 0; j < 16; ++j) dst[j] = f2b(t[kg * 16 + j][nl]);
}

// ---------- layer 0: H0[e] = relu(SA @ W0T[e]^T + b0[e]), bf16 out (full B) ----------
__global__ __launch_bounds__(256, 2)
void k_layer0(const unsigned short* __restrict__ SA,
              const unsigned short* __restrict__ W0T,
              const float* __restrict__ b0,
              unsigned short* __restrict__ H0,
              int Btot) {
    __shared__ unsigned short As[128 * 64];
    __shared__ unsigned short Bs[128 * 64];
    int bm = blockIdx.x, bn = blockIdx.y, e = blockIdx.z;
    int tid = threadIdx.x, lane = tid & 63;
    int wv = tid >> 6, wr = wv >> 1, wc = wv & 1;
    int l15 = lane & 15, kg = lane >> 4;

    const char* Ag = (const char*)(SA + (size_t)(bm * 128) * 64);
    const char* Bg = (const char*)(W0T + ((size_t)e * 1024 + bn * 128) * 64);
#pragma unroll
    for (int it = 0; it < 4; ++it) {
        int off = tid * 16 + it * 4096;
        gload_lds16(Ag + off, (char*)As + off);
        gload_lds16(Bg + off, (char*)Bs + off);
    }
    __syncthreads();

    f32x4 acc[4][4];
#pragma unroll
    for (int mi = 0; mi < 4; ++mi)
#pragma unroll
        for (int ni = 0; ni < 4; ++ni) acc[mi][ni] = (f32x4)0.0f;

#pragma unroll
    for (int ks = 0; ks < 2; ++ks) {
        bf16x8 af[4], bv[4];
#pragma unroll
        for (int mi = 0; mi < 4; ++mi)
            af[mi] = *(const bf16x8*)&As[(wr * 64 + mi * 16 + l15) * 64 + ks * 32 + kg * 8];
#pragma unroll
        for (int ni = 0; ni < 4; ++ni)
            bv[ni] = *(const bf16x8*)&Bs[(wc * 64 + ni * 16 + l15) * 64 + ks * 32 + kg * 8];
#pragma unroll
        for (int mi = 0; mi < 4; ++mi)
#pragma unroll
            for (int ni = 0; ni < 4; ++ni)
                acc[mi][ni] = MFMA16(af[mi], bv[ni], acc[mi][ni]);
    }

    float b0v[4];
#pragma unroll
    for (int ni = 0; ni < 4; ++ni)
        b0v[ni] = b0[e * 1024 + bn * 128 + wc * 64 + ni * 16 + l15];
#pragma unroll
    for (int mi = 0; mi < 4; ++mi)
#pragma unroll
        for (int ni = 0; ni < 4; ++ni)
#pragma unroll
            for (int j = 0; j < 4; ++j) {
                int rloc = bm * 128 + wr * 64 + mi * 16 + kg * 4 + j;
                int col = bn * 128 + wc * 64 + ni * 16 + l15;
                float h = fmaxf(acc[mi][ni][j] + b0v[ni], 0.0f);
                H0[((size_t)e * Btot + rloc) * 1024 + col] = f2b(h);
            }
}

// ---------- fused layer1+mix: mixed = relu(sum_e w[b,e]*relu(H0[e]@W1T[e]^T+b1[e])) ----------
// 256x128 block, 256 thr = 4 waves (2M x 2N) of 128x64 -> 1 wave/SIMD -> 512-reg
// budget: acc[8][4] f32x4 (128) + mix[8][4] f32x4 (128) + frags (~96) fit without
// spill — this is what makes the FUSED mixture possible at the balanced wave shape.
// e-loop inside block: NT = 8*16 = 128 continuous K-tiles; grid 256 = 1 block/CU.
// R10 read-ahead 4-phase schedule per tile:
//   P0: issue bf1[4];  lgkm(4)  -> Q0 frags (from prev P3) ready; MFMA Q0; barrier
//   P1: issue af1[8];  lgkm(8)  -> bf1 ready;                MFMA Q1; barrier
//   P2: stage B(t+2);  lgkm(0)  -> af1 ready;  MFMA Q2; vmcnt(4) [t+1 landed]; barrier
//   P3: issue Q0(t+1) frags[12] + stage A(t+2); MFMA Q3 (regs only); barrier
// WAR: B of buf[t] last-read-complete certified at P1 barrier -> stage B(t+2)@P2 ok;
// A certified at P2 barrier -> stage A(t+2)@P3 ok. FIFO at P2 gate:
// [B(t+1)4 A(t+1)8 B(t+2)4] -> vmcnt(4) certifies exactly tile t+1. Stores only at
// kernel end, so the vmcnt FIFO contains staging loads only.
__global__ __launch_bounds__(256, 1)
void k_fused(const unsigned short* __restrict__ H0,   // [E,Btot,1024]
             const unsigned short* __restrict__ W1T,  // [E,1024(n),1024(k)]
             const float* __restrict__ b1,            // [E,1024]
             const float* __restrict__ wmix,          // [B,8]
             float* __restrict__ mixed,               // [Btot,1024] f32
             int Btot) {
    __shared__ unsigned short As[2][256 * 64];   // 2 x 32 KB
    __shared__ unsigned short Bs[2][128 * 64];   // 2 x 16 KB
    __shared__ float wmixLds[256 * 8];           // 8 KB
    __shared__ float b1Lds[8 * 128];             // 4 KB   (total 108 KB)

    // XCD-coherent decode (xcd = wg%8): all 8 bn-siblings of a bm (sharing the
    // H0 A-panel) land on one XCD's L2. bm ≡ xcd (mod 8), bijective for nbm=32.
    int wg = blockIdx.x;
    int x8 = wg & 7, j = wg >> 3;          // j in [0,32)
    int bm = x8 + ((j >> 3) << 3);
    int bn = j & 7;

    int tid = threadIdx.x, lane = tid & 63;
    int wv = tid >> 6;
    int wr = wv >> 1, wc = wv & 1;         // 2M x 2N waves of 128x64
    int l15 = lane & 15, kg = lane >> 4;
    int k0s = (kg * 16) ^ ((l15 & 7) << 4);
    int k1s = (64 + kg * 16) ^ ((l15 & 7) << 4);

    // staging per-thread offsets: each gload call moves 4 KB (256 thr x 16B) = 32 rows
    int flat = tid * 16;                           // 0..4095
    int srow = flat >> 7;                          // 0..31
    int scol = (flat & 127) ^ ((srow & 7) << 4);   // inverse-swizzled source col

    const char* h0b = (const char*)H0 + (size_t)(bm * 256) * 2048;
    const char* w1b = (const char*)W1T + (size_t)(bn * 128) * 2048;
    size_t eA = (size_t)Btot * 2048;               // H0 per-expert stride (bytes)
    char* Asb = (char*)As;
    char* Bsb = (char*)Bs;

    // fragment read offsets (row&7 == l15&7, matches swizzle)
    int aRow[8], bRow[4];
#pragma unroll
    for (int m = 0; m < 8; ++m) aRow[m] = (wr * 128 + m * 16 + l15) * 128;
#pragma unroll
    for (int n = 0; n < 4; ++n) bRow[n] = (wc * 64 + n * 16 + l15) * 128;

    // preload wmix + b1 into LDS (dynamic-e indexing must be LDS, not regs — rule #20)
    for (int idx = tid; idx < 2048; idx += 256) {
        int r = idx >> 3, e = idx & 7;
        wmixLds[idx] = wmix[(size_t)(bm * 256 + r) * 8 + e];
    }
    for (int idx = tid; idx < 1024; idx += 256)
        b1Lds[idx] = b1[(idx >> 7) * 1024 + bn * 128 + (idx & 127)];
    __syncthreads();   // drains everything (incl. vmcnt) before the pipeline

    auto STAGE_A = [&](int tt) {   // A K-tile: 256x64 = 8 gloads
        int e = tt >> 4, k0b = (tt & 15) << 7;
        const char* s = h0b + (size_t)e * eA + k0b;
        char* d = Asb + (tt & 1) * 32768;
#pragma unroll
        for (int i = 0; i < 8; ++i)
            gload_lds16(s + (size_t)(srow + i * 32) * 2048 + scol, d + flat + i * 4096);
    };
    auto STAGE_B = [&](int tt) {   // B K-tile: 128x64 = 4 gloads
        int e = tt >> 4, k0b = (tt & 15) << 7;
        const char* s = w1b + (size_t)e * (1024 * 2048) + k0b;
        char* d = Bsb + (tt & 1) * 16384;
#pragma unroll
        for (int i = 0; i < 4; ++i)
            gload_lds16(s + (size_t)(srow + i * 32) * 2048 + scol, d + flat + i * 4096);
    };

    const int NT = 128;   // 8 experts x 16 K-tiles

    // prologue: tiles 0,1 (FIFO [B0:4 A0:8 B1:4 A1:8]); vmcnt(12) certifies tile 0
    STAGE_B(0); STAGE_A(0);
    STAGE_B(1); STAGE_A(1);
    asm volatile("s_waitcnt vmcnt(12)" ::: "memory");
    __builtin_amdgcn_s_barrier();

    f32x4 acc[8][4], mix[8][4];
#pragma unroll
    for (int m = 0; m < 8; ++m)
#pragma unroll
        for (int n = 0; n < 4; ++n) { acc[m][n] = (f32x4)0.0f; mix[m][n] = (f32x4)0.0f; }

    bf16x8 af0[4][2], af1[4][2], bf0[2][2], bf1[2][2];

    // pre-issue tile-0 Q0 fragments (12 ds_reads; awaited at P0's lgkm(4))
    {
        const char* Ab = Asb;
        const char* Bb = Bsb;
#pragma unroll
        for (int mi = 0; mi < 4; ++mi) {
            af0[mi][0] = *(const bf16x8*)(Ab + aRow[mi] + k0s);
            af0[mi][1] = *(const bf16x8*)(Ab + aRow[mi] + k1s);
        }
#pragma unroll
        for (int ni = 0; ni < 2; ++ni) {
            bf0[ni][0] = *(const bf16x8*)(Bb + bRow[ni] + k0s);
            bf0[ni][1] = *(const bf16x8*)(Bb + bRow[ni] + k1s);
        }
    }

#pragma unroll 1
    for (int t = 0; t < NT; ++t) {
        int buf = t & 1, nb = buf ^ 1;
        const char* Ab = Asb + buf * 32768;
        const char* Bb = Bsb + buf * 16384;
        const char* AbN = Asb + nb * 32768;
        const char* BbN = Bsb + nb * 16384;

        // ===== P0: issue bf1[4]; lgkm(4) -> Q0 ready; MFMA Q0 (m0-3 x n0-1) =====
#pragma unroll
        for (int ni = 0; ni < 2; ++ni) {
            bf1[ni][0] = *(const bf16x8*)(Bb + bRow[2 + ni] + k0s);
            bf1[ni][1] = *(const bf16x8*)(Bb + bRow[2 + ni] + k1s);
        }
        asm volatile("s_waitcnt lgkmcnt(4)" ::: "memory");
        __builtin_amdgcn_sched_barrier(0);
        __builtin_amdgcn_s_setprio(1);
#pragma unroll
        for (int k = 0; k < 2; ++k)
#pragma unroll
            for (int mi = 0; mi < 4; ++mi)
#pragma unroll
                for (int ni = 0; ni < 2; ++ni)
                    acc[mi][ni] = MFMA16(af0[mi][k], bf0[ni][k], acc[mi][ni]);
        __builtin_amdgcn_s_setprio(0);
        __builtin_amdgcn_sched_barrier(0);
        __builtin_amdgcn_s_barrier();

        // ===== P1: issue af1[8]; lgkm(8) -> bf1 ready; MFMA Q1 (m0-3 x n2-3) =====
#pragma unroll
        for (int mi = 0; mi < 4; ++mi) {
            af1[mi][0] = *(const bf16x8*)(Ab + aRow[4 + mi] + k0s);
            af1[mi][1] = *(const bf16x8*)(Ab + aRow[4 + mi] + k1s);
        }
        asm volatile("s_waitcnt lgkmcnt(8)" ::: "memory");
        __builtin_amdgcn_sched_barrier(0);
        __builtin_amdgcn_s_setprio(1);
#pragma unroll
        for (int k = 0; k < 2; ++k)
#pragma unroll
            for (int mi = 0; mi < 4; ++mi)
#pragma unroll
                for (int ni = 0; ni < 2; ++ni)
                    acc[mi][2 + ni] = MFMA16(af0[mi][k], bf1[ni][k], acc[mi][2 + ni]);
        __builtin_amdgcn_s_setprio(0);
        __builtin_amdgcn_sched_barrier(0);
        __builtin_amdgcn_s_barrier();

        // ===== P2: stage B(t+2); lgkm(0) -> af1 ready; MFMA Q2 (m4-7 x n0-1); vmcnt gate =====
        if (t + 2 < NT) STAGE_B(t + 2);
        asm volatile("s_waitcnt lgkmcnt(0)" ::: "memory");
        __builtin_amdgcn_sched_barrier(0);
        __builtin_amdgcn_s_setprio(1);
#pragma unroll
        for (int k = 0; k < 2; ++k)
#pragma unroll
            for (int mi = 0; mi < 4; ++mi)
#pragma unroll
                for (int ni = 0; ni < 2; ++ni)
                    acc[4 + mi][ni] = MFMA16(af1[mi][k], bf0[ni][k], acc[4 + mi][ni]);
        __builtin_amdgcn_s_setprio(0);
        __builtin_amdgcn_sched_barrier(0);
        if (t + 2 < NT)
            asm volatile("s_waitcnt vmcnt(4)" ::: "memory");   // tile t+1 landed
        else
            asm volatile("s_waitcnt vmcnt(0)" ::: "memory");
        __builtin_amdgcn_s_barrier();

        // ===== P3: issue Q0(t+1) frags[12] + stage A(t+2); MFMA Q3 (m4-7 x n2-3) =====
        if (t + 1 < NT) {
#pragma unroll
            for (int mi = 0; mi < 4; ++mi) {
                af0[mi][0] = *(const bf16x8*)(AbN + aRow[mi] + k0s);
                af0[mi][1] = *(const bf16x8*)(AbN + aRow[mi] + k1s);
            }
#pragma unroll
            for (int ni = 0; ni < 2; ++ni) {
                bf0[ni][0] = *(const bf16x8*)(BbN + bRow[ni] + k0s);
                bf0[ni][1] = *(const bf16x8*)(BbN + bRow[ni] + k1s);
            }
        }
        if (t + 2 < NT) STAGE_A(t + 2);
        __builtin_amdgcn_sched_barrier(0);
        __builtin_amdgcn_s_setprio(1);
#pragma unroll
        for (int k = 0; k < 2; ++k)
#pragma unroll
            for (int mi = 0; mi < 4; ++mi)
#pragma unroll
                for (int ni = 0; ni < 2; ++ni)
                    acc[4 + mi][2 + ni] = MFMA16(af1[mi][k], bf1[ni][k], acc[4 + mi][2 + ni]);
        __builtin_amdgcn_s_setprio(0);
        __builtin_amdgcn_sched_barrier(0);
        __builtin_amdgcn_s_barrier();

        // ===== expert boundary: bias + relu + weighted accumulate (LDS-const only) =====
        if ((t & 15) == 15) {
            int e = t >> 4;
            float b1v[4];
#pragma unroll
            for (int n = 0; n < 4; ++n)
                b1v[n] = b1Lds[e * 128 + wc * 64 + n * 16 + l15];
#pragma unroll
            for (int m = 0; m < 8; ++m)
#pragma unroll
                for (int j = 0; j < 4; ++j) {
                    int lrow = wr * 128 + m * 16 + kg * 4 + j;
                    float w = wmixLds[lrow * 8 + e];
#pragma unroll
                    for (int n = 0; n < 4; ++n) {
                        float h = fmaxf(acc[m][n][j] + b1v[n], 0.0f);
                        mix[m][n][j] += w * h;
                        acc[m][n][j] = 0.0f;
                    }
                }
        }
    }

    // final relu + store mixed f32 (only VMEM stores in the kernel)
#pragma unroll
    for (int m = 0; m < 8; ++m)
#pragma unroll
        for (int n = 0; n < 4; ++n)
#pragma unroll
            for (int j = 0; j < 4; ++j) {
                int row = bm * 256 + wr * 128 + m * 16 + kg * 4 + j;
                int col = bn * 128 + wc * 64 + n * 16 + l15;
                mixed[(size_t)row * 1024 + col] = fmaxf(mix[m][n][j], 0.0f);
            }
}

// ---------- head: q[b] = mixed[b,:] . Wh[c[b],:] + bh[c[b]] ----------
__global__ void k_head(const float* __restrict__ mixed, const float* __restrict__ Wh,
                       const float* __restrict__ bh, const int* __restrict__ c,
                       float* __restrict__ q, int Btot) {
    int row = blockIdx.x * 4 + (threadIdx.x >> 6);
    int lane = threadIdx.x & 63;
    if (row >= Btot) return;
    int ctx = c[row];
    const float4* m4 = (const float4*)(mixed + (size_t)row * 1024);
    const float4* w4 = (const float4*)(Wh + (size_t)ctx * 1024);
    float s = 0.0f;
#pragma unroll
    for (int i = 0; i < 4; ++i) {
        float4 a = m4[lane + i * 64];
        float4 b = w4[lane + i * 64];
        s += a.x * b.x + a.y * b.y + a.z * b.z + a.w * b.w;
    }
#pragma unroll
    for (int off = 32; off > 0; off >>= 1) s += __shfl_down(s, off);
    if (lane == 0) q[row] = s + bh[ctx];
}

// ---------- host ----------
extern "C" void kernel_launch(void* const* d_in, const int* in_sizes, int n_in,
                              void* d_out, int out_size, void* d_ws, size_t ws_size,
                              hipStream_t stream) {
    const float* state  = (const float*)d_in[0];
    const float* action = (const float*)d_in[1];
    const int*   c      = (const int*)d_in[2];
    const float* W0     = (const float*)d_in[3];
    const float* b0     = (const float*)d_in[4];
    const float* W1     = (const float*)d_in[5];
    const float* b1     = (const float*)d_in[6];
    const float* Wte    = (const float*)d_in[7];
    const float* Wh     = (const float*)d_in[8];
    const float* bh     = (const float*)d_in[9];
    float* q = (float*)d_out;
    int B = in_sizes[2];

    // workspace: fixed 17 MB + H0 (full B) 134 MB + mixed f32 33.5 MB = 185 MB
    char* p = (char*)d_ws;
    unsigned short* W1T = (unsigned short*)p; p += (size_t)8 * 1024 * 1024 * 2;  // 16 MB
    unsigned short* W0T = (unsigned short*)p; p += (size_t)8 * 1024 * 64 * 2;    // 1 MB
    unsigned short* SA  = (unsigned short*)p; p += (size_t)B * 64 * 2;
    float* wmix         = (float*)p;          p += (size_t)B * 8 * 4;
    unsigned short* H0  = (unsigned short*)p; p += (size_t)8 * B * 1024 * 2;
    float* mixed        = (float*)p;

    k_prep_sa<<<(B + 255) / 256, 256, 0, stream>>>(state, action, c, Wte, SA, wmix, B);
    k_prep_w0t<<<(8 * 1024) / 256, 256, 0, stream>>>(W0, W0T);
    k_prep_w1t<<<dim3(16, 16, 8), 256, 0, stream>>>(W1, W1T);
    k_layer0<<<dim3(B / 128, 8, 8), 256, 0, stream>>>(SA, W0T, b0, H0, B);
    k_fused<<<(B / 256) * 8, 256, 0, stream>>>(H0, W1T, b1, wmix, mixed, B);
    k_head<<<(B + 3) / 4, 256, 0, stream>>>(mixed, Wh, bh, c, q, B);
}

// Round 12
// 223.034 us; speedup vs baseline: 1.9023x; 1.9023x over previous
//
#include <hip/hip_runtime.h>
#include <hip/hip_bf16.h>
#include <stdint.h>

// ---------- types ----------
typedef __attribute__((ext_vector_type(8))) __bf16 bf16x8;
typedef __attribute__((ext_vector_type(4))) float f32x4;

__device__ __forceinline__ unsigned short f2b(float f) {
    return __builtin_bit_cast(unsigned short, __float2bfloat16(f));
}

// async global -> LDS, 16B per lane (wave-uniform base + lane*16 dest order)
__device__ __forceinline__ void gload_lds16(const void* g, void* l) {
    __builtin_amdgcn_global_load_lds(
        (__attribute__((address_space(1))) void*)(uintptr_t)g,
        (__attribute__((address_space(3))) void*)l,
        16, 0, 0);
}

#define MFMA16(a, b, c) __builtin_amdgcn_mfma_f32_16x16x32_bf16((a), (b), (c), 0, 0, 0)

// ---------- constants ----------
// B=8192, S=39, A=4, D_IN=43 (pad 64), F=1024, E=8, C=10

// ---------- prep: SA pack + mixture weights ----------
__global__ void k_prep_sa(const float* __restrict__ state, const float* __restrict__ action,
                          const int* __restrict__ c, const float* __restrict__ Wte,
                          unsigned short* __restrict__ SA, float* __restrict__ wmix, int B) {
    int b = blockIdx.x * 256 + threadIdx.x;
    if (b >= B) return;
    unsigned short* row = SA + (size_t)b * 64;
#pragma unroll
    for (int i = 0; i < 39; ++i) row[i] = f2b(state[(size_t)b * 39 + i]);
#pragma unroll
    for (int i = 0; i < 4; ++i) row[39 + i] = f2b(action[(size_t)b * 4 + i]);
#pragma unroll
    for (int i = 43; i < 64; ++i) row[i] = 0;
    int ctx = c[b];
#pragma unroll
    for (int e = 0; e < 8; ++e) wmix[(size_t)b * 8 + e] = Wte[e * 10 + ctx];
}

// ---------- prep: W0 [E,43,1024] f32 -> W0T [E,1024,64] bf16 ----------
__global__ void k_prep_w0t(const float* __restrict__ W0, unsigned short* __restrict__ W0T) {
    int idx = blockIdx.x * 256 + threadIdx.x;   // e*1024 + f
    int e = idx >> 10, f = idx & 1023;
    unsigned short* dst = W0T + (size_t)idx * 64;
#pragma unroll 1
    for (int k = 0; k < 43; ++k) dst[k] = f2b(W0[((size_t)e * 43 + k) * 1024 + f]);
#pragma unroll
    for (int k = 43; k < 64; ++k) dst[k] = 0;
}

// ---------- prep: W1 [E,1024,1024] f32 -> W1T [E,1024(n),1024(k)] bf16 ----------
__global__ void k_prep_w1t(const float* __restrict__ W1, unsigned short* __restrict__ W1T) {
    __shared__ float t[64][65];
    int k0 = blockIdx.x * 64, n0 = blockIdx.y * 64, e = blockIdx.z;
    int tid = threadIdx.x;
    int cl = tid & 63, rg = tid >> 6;
    const float* src = W1 + ((size_t)e * 1024 + k0) * 1024 + n0;
#pragma unroll
    for (int i = 0; i < 16; ++i) {
        int kr = rg * 16 + i;
        t[kr][cl] = src[(size_t)kr * 1024 + cl];
    }
    __syncthreads();
    int nl = tid >> 2, kg = tid & 3;
    unsigned short* dst = W1T + ((size_t)e * 1024 + n0 + nl) * 1024 + k0 + kg * 16;
#pragma unroll
    for (int j = 0; j < 16; ++j) dst[j] = f2b(t[kg * 16 + j][nl]);
}

// ---------- layer 0: H0[e] = relu(SA @ W0T[e]^T + b0[e]), bf16 out (full B) ----------
__global__ __launch_bounds__(256, 2)
void k_layer0(const unsigned short* __restrict__ SA,
              const unsigned short* __restrict__ W0T,
              const float* __restrict__ b0,
              unsigned short* __restrict__ H0,
              int Btot) {
    __shared__ unsigned short As[128 * 64];
    __shared__ unsigned short Bs[128 * 64];
    int bm = blockIdx.x, bn = blockIdx.y, e = blockIdx.z;
    int tid = threadIdx.x, lane = tid & 63;
    int wv = tid >> 6, wr = wv >> 1, wc = wv & 1;
    int l15 = lane & 15, kg = lane >> 4;

    const char* Ag = (const char*)(SA + (size_t)(bm * 128) * 64);
    const char* Bg = (const char*)(W0T + ((size_t)e * 1024 + bn * 128) * 64);
#pragma unroll
    for (int it = 0; it < 4; ++it) {
        int off = tid * 16 + it * 4096;
        gload_lds16(Ag + off, (char*)As + off);
        gload_lds16(Bg + off, (char*)Bs + off);
    }
    __syncthreads();

    f32x4 acc[4][4];
#pragma unroll
    for (int mi = 0; mi < 4; ++mi)
#pragma unroll
        for (int ni = 0; ni < 4; ++ni) acc[mi][ni] = (f32x4)0.0f;

#pragma unroll
    for (int ks = 0; ks < 2; ++ks) {
        bf16x8 af[4], bv[4];
#pragma unroll
        for (int mi = 0; mi < 4; ++mi)
            af[mi] = *(const bf16x8*)&As[(wr * 64 + mi * 16 + l15) * 64 + ks * 32 + kg * 8];
#pragma unroll
        for (int ni = 0; ni < 4; ++ni)
            bv[ni] = *(const bf16x8*)&Bs[(wc * 64 + ni * 16 + l15) * 64 + ks * 32 + kg * 8];
#pragma unroll
        for (int mi = 0; mi < 4; ++mi)
#pragma unroll
            for (int ni = 0; ni < 4; ++ni)
                acc[mi][ni] = MFMA16(af[mi], bv[ni], acc[mi][ni]);
    }

    float b0v[4];
#pragma unroll
    for (int ni = 0; ni < 4; ++ni)
        b0v[ni] = b0[e * 1024 + bn * 128 + wc * 64 + ni * 16 + l15];
#pragma unroll
    for (int mi = 0; mi < 4; ++mi)
#pragma unroll
        for (int ni = 0; ni < 4; ++ni)
#pragma unroll
            for (int j = 0; j < 4; ++j) {
                int rloc = bm * 128 + wr * 64 + mi * 16 + kg * 4 + j;
                int col = bn * 128 + wc * 64 + ni * 16 + l15;
                float h = fmaxf(acc[mi][ni][j] + b0v[ni], 0.0f);
                H0[((size_t)e * Btot + rloc) * 1024 + col] = f2b(h);
            }
}

// ---------- fused layer1 + mixture + HEAD ----------
// q[b] += sum over this block's 128 cols of relu(sum_e w[b,e]*relu(H0@W1T^T+b1)) . Wh[c[b]]
// 128x128 block, 256 thr = 4 waves (2M x 2N) of 64x64; BK=64, dbuf; 2 blocks/CU (72KB).
// Read-ahead 4-phase schedule (R10 mechanism at R6 geometry):
//   P0: issue bf1[4]; lgkm(4) [drains prev-P3's 8 Q0 frags]; 8 MFMA Q0(m01xn01); barrier
//   P1: issue af1[4]; lgkm(4) [drains bf1];                  8 MFMA Q1(m01xn23); barrier
//   P2: stage B(t+2)[4]; lgkm(0) [drains af1]; 8 MFMA Q2(m23xn01); vmcnt(4) gate; barrier
//   P3: issue Q0(t+1) frags[8] + stage A(t+2)[4]; 8 MFMA Q3(m23xn23) from regs; barrier
// WAR: B-region of buf[t] reads complete by P1's lgkm (P1-end barrier certifies all
// waves) -> B(t+2) staging @P2 safe; A-region by P2's lgkm(0) -> A(t+2) @P3 safe.
// FIFO at P2 gate: [B(t+1):4, A(t+1):4, B(t+2):4] -> vmcnt(4) certifies tile t+1,
// so P3's Q0(t+1) reads are safe. Never drains to 0 mid-loop.
// Head fused in epilogue: per-row partial dot + shfl reduce + atomicAdd (q pre-zeroed).
__global__ __launch_bounds__(256, 2)
void k_fused(const unsigned short* __restrict__ H0,   // [E,Btot,1024]
             const unsigned short* __restrict__ W1T,  // [E,1024(n),1024(k)]
             const float* __restrict__ b1,            // [E,1024]
             const float* __restrict__ wmix,          // [B,8]
             const float* __restrict__ Wh,            // [C,1024]
             const float* __restrict__ bh,            // [C]
             const int* __restrict__ c,               // [B]
             float* __restrict__ q,                   // [B] (zeroed)
             int Btot) {
    __shared__ unsigned short As[2][128 * 64];   // 2 x 16 KB
    __shared__ unsigned short Bs[2][128 * 64];   // 2 x 16 KB
    __shared__ float wmixLds[128 * 8];           // 4 KB
    __shared__ float b1Lds[8 * 128];             // 4 KB   (72 KB total)

    int nbm = Btot / 128;
    int wg = blockIdx.x;
    // XCD-coherent (xcd = wg%8): all 8 bn-siblings of a bm on one XCD's L2.
    int bm, bn;
    if ((nbm & 7) == 0) {
        int xcd = wg & 7, j = wg >> 3;
        bm = xcd + ((j >> 3) << 3);
        bn = j & 7;
    } else {
        bm = wg >> 3; bn = wg & 7;
    }

    int tid = threadIdx.x, lane = tid & 63;
    int wv = tid >> 6;
    int wr = wv >> 1, wc = wv & 1;               // 2M x 2N waves of 64x64
    int l15 = lane & 15, kg = lane >> 4;
    int k0s = (kg * 16) ^ ((l15 & 7) << 4);
    int k1s = (64 + kg * 16) ^ ((l15 & 7) << 4);

    // staging map: 16B/lane; one operand K-tile (128x64 = 16 KB) = 4 gloads
    int flat = tid * 16;                           // 0..4095
    int srow = flat >> 7;                          // 0..31
    int scol = (flat & 127) ^ ((srow & 7) << 4);   // inverse-swizzled source col

    const char* h0b = (const char*)H0 + (size_t)(bm * 128) * 2048;
    const char* w1b = (const char*)W1T + (size_t)(bn * 128) * 2048;
    size_t eA = (size_t)Btot * 2048;
    char* Asb = (char*)As;
    char* Bsb = (char*)Bs;

    // fragment read offsets (row&7 == l15&7 matches swizzle)
    int aOff[4], bOff[4];
#pragma unroll
    for (int m = 0; m < 4; ++m) aOff[m] = (wr * 64 + m * 16 + l15) * 128;
#pragma unroll
    for (int n = 0; n < 4; ++n) bOff[n] = (wc * 64 + n * 16 + l15) * 128;

    // preload wmix + b1 into LDS
    for (int idx = tid; idx < 1024; idx += 256) {
        int r = idx >> 3, e = idx & 7;
        wmixLds[idx] = wmix[(size_t)(bm * 128 + r) * 8 + e];
    }
    for (int idx = tid; idx < 1024; idx += 256)
        b1Lds[idx] = b1[(idx >> 7) * 1024 + bn * 128 + (idx & 127)];
    __syncthreads();   // full drain before the pipeline

    auto STAGE_A = [&](int tt) {
        int e = tt >> 4, k0b = (tt & 15) << 7;
        const char* s = h0b + (size_t)e * eA + k0b;
        char* d = Asb + (tt & 1) * 16384;
#pragma unroll
        for (int i = 0; i < 4; ++i)
            gload_lds16(s + (size_t)(srow + i * 32) * 2048 + scol, d + flat + i * 4096);
    };
    auto STAGE_B = [&](int tt) {
        int e = tt >> 4, k0b = (tt & 15) << 7;
        const char* s = w1b + (size_t)e * (1024 * 2048) + k0b;
        char* d = Bsb + (tt & 1) * 16384;
#pragma unroll
        for (int i = 0; i < 4; ++i)
            gload_lds16(s + (size_t)(srow + i * 32) * 2048 + scol, d + flat + i * 4096);
    };

    const int NT = 128;   // 8 experts x 16 K-tiles

    // prologue: tiles 0,1 (FIFO [B0:4 A0:4 B1:4 A1:4]); vmcnt(8) certifies tile 0
    STAGE_B(0); STAGE_A(0);
    STAGE_B(1); STAGE_A(1);
    asm volatile("s_waitcnt vmcnt(8)" ::: "memory");
    __builtin_amdgcn_s_barrier();

    f32x4 acc[4][4], mix[4][4];
#pragma unroll
    for (int m = 0; m < 4; ++m)
#pragma unroll
        for (int n = 0; n < 4; ++n) { acc[m][n] = (f32x4)0.0f; mix[m][n] = (f32x4)0.0f; }

    bf16x8 af0[2][2], af1[2][2], bf0[2][2], bf1[2][2];

    // pre-issue tile-0 Q0 fragments (8 ds_reads; drained at P0's lgkm(4))
    {
        const char* Ab = Asb;
        const char* Bb = Bsb;
#pragma unroll
        for (int mi = 0; mi < 2; ++mi) {
            af0[mi][0] = *(const bf16x8*)(Ab + aOff[mi] + k0s);
            af0[mi][1] = *(const bf16x8*)(Ab + aOff[mi] + k1s);
        }
#pragma unroll
        for (int ni = 0; ni < 2; ++ni) {
            bf0[ni][0] = *(const bf16x8*)(Bb + bOff[ni] + k0s);
            bf0[ni][1] = *(const bf16x8*)(Bb + bOff[ni] + k1s);
        }
    }

#pragma unroll 1
    for (int t = 0; t < NT; ++t) {
        int buf = t & 1, nb = buf ^ 1;
        const char* Ab = Asb + buf * 16384;
        const char* Bb = Bsb + buf * 16384;
        const char* AbN = Asb + nb * 16384;
        const char* BbN = Bsb + nb * 16384;

        // ===== P0: issue bf1[4]; lgkm(4); MFMA Q0 (m01 x n01) =====
#pragma unroll
        for (int ni = 0; ni < 2; ++ni) {
            bf1[ni][0] = *(const bf16x8*)(Bb + bOff[2 + ni] + k0s);
            bf1[ni][1] = *(const bf16x8*)(Bb + bOff[2 + ni] + k1s);
        }
        asm volatile("s_waitcnt lgkmcnt(4)" ::: "memory");
        __builtin_amdgcn_sched_barrier(0);
        __builtin_amdgcn_s_setprio(1);
#pragma unroll
        for (int k = 0; k < 2; ++k)
#pragma unroll
            for (int mi = 0; mi < 2; ++mi)
#pragma unroll
                for (int ni = 0; ni < 2; ++ni)
                    acc[mi][ni] = MFMA16(af0[mi][k], bf0[ni][k], acc[mi][ni]);
        __builtin_amdgcn_s_setprio(0);
        __builtin_amdgcn_sched_barrier(0);
        __builtin_amdgcn_s_barrier();

        // ===== P1: issue af1[4]; lgkm(4); MFMA Q1 (m01 x n23) =====
#pragma unroll
        for (int mi = 0; mi < 2; ++mi) {
            af1[mi][0] = *(const bf16x8*)(Ab + aOff[2 + mi] + k0s);
            af1[mi][1] = *(const bf16x8*)(Ab + aOff[2 + mi] + k1s);
        }
        asm volatile("s_waitcnt lgkmcnt(4)" ::: "memory");
        __builtin_amdgcn_sched_barrier(0);
        __builtin_amdgcn_s_setprio(1);
#pragma unroll
        for (int k = 0; k < 2; ++k)
#pragma unroll
            for (int mi = 0; mi < 2; ++mi)
#pragma unroll
                for (int ni = 0; ni < 2; ++ni)
                    acc[mi][2 + ni] = MFMA16(af0[mi][k], bf1[ni][k], acc[mi][2 + ni]);
        __builtin_amdgcn_s_setprio(0);
        __builtin_amdgcn_sched_barrier(0);
        __builtin_amdgcn_s_barrier();   // all waves' bf1 reads complete -> B region free

        // ===== P2: stage B(t+2); lgkm(0); MFMA Q2 (m23 x n01); vmcnt gate =====
        if (t + 2 < NT) STAGE_B(t + 2);
        asm volatile("s_waitcnt lgkmcnt(0)" ::: "memory");
        __builtin_amdgcn_sched_barrier(0);
        __builtin_amdgcn_s_setprio(1);
#pragma unroll
        for (int k = 0; k < 2; ++k)
#pragma unroll
            for (int mi = 0; mi < 2; ++mi)
#pragma unroll
                for (int ni = 0; ni < 2; ++ni)
                    acc[2 + mi][ni] = MFMA16(af1[mi][k], bf0[ni][k], acc[2 + mi][ni]);
        __builtin_amdgcn_s_setprio(0);
        __builtin_amdgcn_sched_barrier(0);
        if (t + 2 < NT)
            asm volatile("s_waitcnt vmcnt(4)" ::: "memory");   // tile t+1 landed
        else
            asm volatile("s_waitcnt vmcnt(0)" ::: "memory");
        __builtin_amdgcn_s_barrier();   // A region free + buf[t+1] certified

        // ===== P3: issue Q0(t+1)[8] + stage A(t+2); MFMA Q3 (m23 x n23, regs) =====
        if (t + 1 < NT) {
#pragma unroll
            for (int mi = 0; mi < 2; ++mi) {
                af0[mi][0] = *(const bf16x8*)(AbN + aOff[mi] + k0s);
                af0[mi][1] = *(const bf16x8*)(AbN + aOff[mi] + k1s);
            }
#pragma unroll
            for (int ni = 0; ni < 2; ++ni) {
                bf0[ni][0] = *(const bf16x8*)(BbN + bOff[ni] + k0s);
                bf0[ni][1] = *(const bf16x8*)(BbN + bOff[ni] + k1s);
            }
        }
        if (t + 2 < NT) STAGE_A(t + 2);
        __builtin_amdgcn_sched_barrier(0);
        __builtin_amdgcn_s_setprio(1);
#pragma unroll
        for (int k = 0; k < 2; ++k)
#pragma unroll
            for (int mi = 0; mi < 2; ++mi)
#pragma unroll
                for (int ni = 0; ni < 2; ++ni)
                    acc[2 + mi][2 + ni] = MFMA16(af1[mi][k], bf1[ni][k], acc[2 + mi][2 + ni]);
        __builtin_amdgcn_s_setprio(0);
        __builtin_amdgcn_sched_barrier(0);
        __builtin_amdgcn_s_barrier();

        // ===== expert boundary: bias + relu + weighted accumulate =====
        if ((t & 15) == 15) {
            int e = t >> 4;
            float b1v[4];
#pragma unroll
            for (int n = 0; n < 4; ++n)
                b1v[n] = b1Lds[e * 128 + wc * 64 + n * 16 + l15];
#pragma unroll
            for (int m = 0; m < 4; ++m)
#pragma unroll
                for (int j = 0; j < 4; ++j) {
                    int lrow = wr * 64 + m * 16 + kg * 4 + j;
                    float w = wmixLds[lrow * 8 + e];
#pragma unroll
                    for (int n = 0; n < 4; ++n) {
                        float h = fmaxf(acc[m][n][j] + b1v[n], 0.0f);
                        mix[m][n][j] += w * h;
                        acc[m][n][j] = 0.0f;
                    }
                }
        }
    }

    // ===== fused head: per-row partial dot over this block's 128 cols =====
    // cols of this lane: bn*128 + wc*64 + n*16 + l15. Reduce over l15 (16 lanes),
    // atomicAdd one partial per (row, wc-wave). bh added once by (bn==0,wc==0).
#pragma unroll
    for (int m = 0; m < 4; ++m)
#pragma unroll
        for (int j = 0; j < 4; ++j) {
            int grow = bm * 128 + wr * 64 + m * 16 + kg * 4 + j;
            int ctx = c[grow];
            const float* whp = Wh + (size_t)ctx * 1024 + bn * 128 + wc * 64;
            float s = 0.0f;
#pragma unroll
            for (int n = 0; n < 4; ++n)
                s += fmaxf(mix[m][n][j], 0.0f) * whp[n * 16 + l15];
            s += __shfl_xor(s, 1);
            s += __shfl_xor(s, 2);
            s += __shfl_xor(s, 4);
            s += __shfl_xor(s, 8);
            if (l15 == 0) {
                if (bn == 0 && wc == 0) s += bh[ctx];
                atomicAdd(q + grow, s);
            }
        }
}

// ---------- host ----------
extern "C" void kernel_launch(void* const* d_in, const int* in_sizes, int n_in,
                              void* d_out, int out_size, void* d_ws, size_t ws_size,
                              hipStream_t stream) {
    const float* state  = (const float*)d_in[0];
    const float* action = (const float*)d_in[1];
    const int*   c      = (const int*)d_in[2];
    const float* W0     = (const float*)d_in[3];
    const float* b0     = (const float*)d_in[4];
    const float* W1     = (const float*)d_in[5];
    const float* b1     = (const float*)d_in[6];
    const float* Wte    = (const float*)d_in[7];
    const float* Wh     = (const float*)d_in[8];
    const float* bh     = (const float*)d_in[9];
    float* q = (float*)d_out;
    int B = in_sizes[2];

    // workspace: 17 MB fixed + H0 full-B 134 MB
    char* p = (char*)d_ws;
    unsigned short* W1T = (unsigned short*)p; p += (size_t)8 * 1024 * 1024 * 2;  // 16 MB
    unsigned short* W0T = (unsigned short*)p; p += (size_t)8 * 1024 * 64 * 2;    // 1 MB
    unsigned short* SA  = (unsigned short*)p; p += (size_t)B * 64 * 2;
    float* wmix         = (float*)p;          p += (size_t)B * 8 * 4;
    unsigned short* H0  = (unsigned short*)p;

    hipMemsetAsync(q, 0, (size_t)B * 4, stream);   // q accumulated via atomics

    k_prep_sa<<<(B + 255) / 256, 256, 0, stream>>>(state, action, c, Wte, SA, wmix, B);
    k_prep_w0t<<<(8 * 1024) / 256, 256, 0, stream>>>(W0, W0T);
    k_prep_w1t<<<dim3(16, 16, 8), 256, 0, stream>>>(W1, W1T);
    k_layer0<<<dim3(B / 128, 8, 8), 256, 0, stream>>>(SA, W0T, b0, H0, B);
    k_fused<<<(B / 128) * 8, 256, 0, stream>>>(H0, W1T, b1, wmix, Wh, bh, c, q, B);
}

// Round 13
// 206.157 us; speedup vs baseline: 2.0580x; 1.0819x over previous
//
#include <hip/hip_runtime.h>
#include <hip/hip_bf16.h>
#include <stdint.h>

// ---------- types ----------
typedef __attribute__((ext_vector_type(8))) __bf16 bf16x8;
typedef __attribute__((ext_vector_type(4))) float f32x4;

__device__ __forceinline__ unsigned short f2b(float f) {
    return __builtin_bit_cast(unsigned short, __float2bfloat16(f));
}

// async global -> LDS, 16B per lane (wave-uniform base + lane*16 dest order)
__device__ __forceinline__ void gload_lds16(const void* g, void* l) {
    __builtin_amdgcn_global_load_lds(
        (__attribute__((address_space(1))) void*)(uintptr_t)g,
        (__attribute__((address_space(3))) void*)l,
        16, 0, 0);
}

#define MFMA16(a, b, c) __builtin_amdgcn_mfma_f32_16x16x32_bf16((a), (b), (c), 0, 0, 0)

// ---------- constants ----------
// B=8192, S=39, A=4, D_IN=43 (pad 64), F=1024, E=8, C=10

// ---------- prep: SA pack + mixture weights ----------
__global__ void k_prep_sa(const float* __restrict__ state, const float* __restrict__ action,
                          const int* __restrict__ c, const float* __restrict__ Wte,
                          unsigned short* __restrict__ SA, float* __restrict__ wmix, int B) {
    int b = blockIdx.x * 256 + threadIdx.x;
    if (b >= B) return;
    unsigned short* row = SA + (size_t)b * 64;
#pragma unroll
    for (int i = 0; i < 39; ++i) row[i] = f2b(state[(size_t)b * 39 + i]);
#pragma unroll
    for (int i = 0; i < 4; ++i) row[39 + i] = f2b(action[(size_t)b * 4 + i]);
#pragma unroll
    for (int i = 43; i < 64; ++i) row[i] = 0;
    int ctx = c[b];
#pragma unroll
    for (int e = 0; e < 8; ++e) wmix[(size_t)b * 8 + e] = Wte[e * 10 + ctx];
}

// ---------- prep: W0 [E,43,1024] f32 -> W0T [E,1024,64] bf16 ----------
__global__ void k_prep_w0t(const float* __restrict__ W0, unsigned short* __restrict__ W0T) {
    int idx = blockIdx.x * 256 + threadIdx.x;   // e*1024 + f
    int e = idx >> 10, f = idx & 1023;
    unsigned short* dst = W0T + (size_t)idx * 64;
#pragma unroll 1
    for (int k = 0; k < 43; ++k) dst[k] = f2b(W0[((size_t)e * 43 + k) * 1024 + f]);
#pragma unroll
    for (int k = 43; k < 64; ++k) dst[k] = 0;
}

// ---------- prep: W1 [E,1024,1024] f32 -> W1T [E,1024(n),1024(k)] bf16 ----------
__global__ void k_prep_w1t(const float* __restrict__ W1, unsigned short* __restrict__ W1T) {
    __shared__ float t[64][65];
    int k0 = blockIdx.x * 64, n0 = blockIdx.y * 64, e = blockIdx.z;
    int tid = threadIdx.x;
    int cl = tid & 63, rg = tid >> 6;
    const float* src = W1 + ((size_t)e * 1024 + k0) * 1024 + n0;
#pragma unroll
    for (int i = 0; i < 16; ++i) {
        int kr = rg * 16 + i;
        t[kr][cl] = src[(size_t)kr * 1024 + cl];
    }
    __syncthreads();
    int nl = tid >> 2, kg = tid & 3;
    unsigned short* dst = W1T + ((size_t)e * 1024 + n0 + nl) * 1024 + k0 + kg * 16;
#pragma unroll
    for (int j = 0; j < 16; ++j) dst[j] = f2b(t[kg * 16 + j][nl]);
}

// ---------- layer 0: H0[e] = relu(SA @ W0T[e]^T + b0[e]), bf16 out (full B) ----------
__global__ __launch_bounds__(256, 2)
void k_layer0(const unsigned short* __restrict__ SA,
              const unsigned short* __restrict__ W0T,
              const float* __restrict__ b0,
              unsigned short* __restrict__ H0,
              int Btot) {
    __shared__ unsigned short As[128 * 64];
    __shared__ unsigned short Bs[128 * 64];
    int bm = blockIdx.x, bn = blockIdx.y, e = blockIdx.z;
    int tid = threadIdx.x, lane = tid & 63;
    int wv = tid >> 6, wr = wv >> 1, wc = wv & 1;
    int l15 = lane & 15, kg = lane >> 4;

    const char* Ag = (const char*)(SA + (size_t)(bm * 128) * 64);
    const char* Bg = (const char*)(W0T + ((size_t)e * 1024 + bn * 128) * 64);
#pragma unroll
    for (int it = 0; it < 4; ++it) {
        int off = tid * 16 + it * 4096;
        gload_lds16(Ag + off, (char*)As + off);
        gload_lds16(Bg + off, (char*)Bs + off);
    }
    __syncthreads();

    f32x4 acc[4][4];
#pragma unroll
    for (int mi = 0; mi < 4; ++mi)
#pragma unroll
        for (int ni = 0; ni < 4; ++ni) acc[mi][ni] = (f32x4)0.0f;

#pragma unroll
    for (int ks = 0; ks < 2; ++ks) {
        bf16x8 af[4], bv[4];
#pragma unroll
        for (int mi = 0; mi < 4; ++mi)
            af[mi] = *(const bf16x8*)&As[(wr * 64 + mi * 16 + l15) * 64 + ks * 32 + kg * 8];
#pragma unroll
        for (int ni = 0; ni < 4; ++ni)
            bv[ni] = *(const bf16x8*)&Bs[(wc * 64 + ni * 16 + l15) * 64 + ks * 32 + kg * 8];
#pragma unroll
        for (int mi = 0; mi < 4; ++mi)
#pragma unroll
            for (int ni = 0; ni < 4; ++ni)
                acc[mi][ni] = MFMA16(af[mi], bv[ni], acc[mi][ni]);
    }

    float b0v[4];
#pragma unroll
    for (int ni = 0; ni < 4; ++ni)
        b0v[ni] = b0[e * 1024 + bn * 128 + wc * 64 + ni * 16 + l15];
#pragma unroll
    for (int mi = 0; mi < 4; ++mi)
#pragma unroll
        for (int ni = 0; ni < 4; ++ni)
#pragma unroll
            for (int j = 0; j < 4; ++j) {
                int rloc = bm * 128 + wr * 64 + mi * 16 + kg * 4 + j;
                int col = bn * 128 + wc * 64 + ni * 16 + l15;
                float h = fmaxf(acc[mi][ni][j] + b0v[ni], 0.0f);
                H0[((size_t)e * Btot + rloc) * 1024 + col] = f2b(h);
            }
}

// ---------- fused layer1 + mixture + head (R6 2-phase schedule + R12 head epilogue) ----------
// q[b] += sum over this block's 128 cols of relu(sum_e w[b,e]*relu(H0@W1T^T+b1)) . Wh[c[b]]
// 128x128 block, 256 thr = 4 waves (2M x 2N) of 64x64; BK=64, dbuf, 72 KB -> 2 blocks/CU.
// Per K-tile: 2 phases of 16 MFMA; reads+stages issued BEFORE the barrier (barrier
// arrival skew absorbs LDS latency). Stage split {B0..B3,A0,A2} (PA) / {A1,A3} (PB);
// FIFO gates: after PA vmcnt(6) certifies PB's data; after PB vmcnt(2) certifies PA(t+1).
// Each phase drains lgkmcnt(0) before its trailing barrier -> buffer reuse race-free.
// (This exact loop measured 152 µs / MfmaUtil 39% in R6 — best of 12 rounds.)
__global__ __launch_bounds__(256, 2)
void k_fused(const unsigned short* __restrict__ H0,   // [E,Btot,1024]
             const unsigned short* __restrict__ W1T,  // [E,1024(n),1024(k)]
             const float* __restrict__ b1,            // [E,1024]
             const float* __restrict__ wmix,          // [B,8]
             const float* __restrict__ Wh,            // [C,1024]
             const float* __restrict__ bh,            // [C]
             const int* __restrict__ c,               // [B]
             float* __restrict__ q,                   // [B] (pre-zeroed)
             int Btot) {
    __shared__ unsigned short As[2][128 * 64];   // 2 x 16 KB
    __shared__ unsigned short Bs[2][128 * 64];   // 2 x 16 KB
    __shared__ float wmixLds[128 * 8];           // 4 KB
    __shared__ float b1Lds[8 * 128];             // 4 KB   (72 KB total)

    int nbm = Btot / 128;
    int wg = blockIdx.x;
    // XCD-coherent (xcd = wg%8): the 8 bn-siblings of a bm on one XCD's L2.
    int bm, bn;
    if ((nbm & 7) == 0) {
        int xcd = wg & 7, j = wg >> 3;
        bm = xcd + ((j >> 3) << 3);
        bn = j & 7;
    } else {
        bm = wg >> 3; bn = wg & 7;
    }

    int tid = threadIdx.x, lane = tid & 63;
    int wv = tid >> 6;
    int wr = wv >> 1, wc = wv & 1;                // 2M x 2N wave grid
    int l15 = lane & 15, kg = lane >> 4;
    int kg16 = kg * 16;
    int xsw = (l15 & 7) << 4;

    // staging maps: 16B/lane; A and B each 4 issues of 4KB (rows of 128B)
    int tid16 = tid * 16;
    int sSrc[4], sDst[4];
#pragma unroll
    for (int i = 0; i < 4; ++i) {
        int flat = tid16 + i * 4096;
        int row = flat >> 7, colb = flat & 127;
        sDst[i] = flat;
        sSrc[i] = row * 2048 + (colb ^ ((row & 7) << 4));   // inverse-swizzled source
    }

    const char* h0base = (const char*)H0 + (size_t)(bm * 128) * 2048;
    const char* w1base = (const char*)W1T + (size_t)(bn * 128) * 2048;
    size_t eAstride = (size_t)Btot * 2048;

    // fragment read offsets (swizzled; row&7 == l15&7)
    int aOff[4], bOff[4];
#pragma unroll
    for (int m = 0; m < 4; ++m) aOff[m] = (wr * 64 + m * 16 + l15) * 128;
#pragma unroll
    for (int n = 0; n < 4; ++n) bOff[n] = (wc * 64 + n * 16 + l15) * 128;

    // preload wmix + b1 into LDS (keeps the K-loop vmcnt-silent)
    for (int idx = tid; idx < 1024; idx += 256) {
        int r = idx >> 3, e = idx & 7;
        wmixLds[idx] = wmix[(size_t)(bm * 128 + r) * 8 + e];
    }
    for (int idx = tid; idx < 1024; idx += 256)
        b1Lds[idx] = b1[(idx >> 7) * 1024 + bn * 128 + (idx & 127)];
    __syncthreads();   // full drain before the pipeline starts

    f32x4 acc[4][4], mix[4][4];
#pragma unroll
    for (int m = 0; m < 4; ++m)
#pragma unroll
        for (int n = 0; n < 4; ++n) { acc[m][n] = (f32x4)0.0f; mix[m][n] = (f32x4)0.0f; }

    const int NT = 128;   // 8 experts * 16 K-tiles

    auto STAGE_PA = [&](int tt) {   // B full tile + A row-groups 0,2
        int e = tt >> 4;
        int k0b = (tt & 15) << 7;
        const char* Ab = h0base + (size_t)e * eAstride + k0b;
        const char* Bb = w1base + (size_t)e * (1024 * 2048) + k0b;
        char* Ad = (char*)As[tt & 1];
        char* Bd = (char*)Bs[tt & 1];
        gload_lds16(Bb + sSrc[0], Bd + sDst[0]);
        gload_lds16(Bb + sSrc[1], Bd + sDst[1]);
        gload_lds16(Bb + sSrc[2], Bd + sDst[2]);
        gload_lds16(Bb + sSrc[3], Bd + sDst[3]);
        gload_lds16(Ab + sSrc[0], Ad + sDst[0]);
        gload_lds16(Ab + sSrc[2], Ad + sDst[2]);
    };
    auto STAGE_PB = [&](int tt) {   // A row-groups 1,3
        int e = tt >> 4;
        int k0b = (tt & 15) << 7;
        const char* Ab = h0base + (size_t)e * eAstride + k0b;
        char* Ad = (char*)As[tt & 1];
        gload_lds16(Ab + sSrc[1], Ad + sDst[1]);
        gload_lds16(Ab + sSrc[3], Ad + sDst[3]);
    };

#define KB0 ((kg16) ^ xsw)
#define KB1 ((64 + kg16) ^ xsw)

    // prologue: stage tile 0; gate phase-A's 6 loads (2 may still fly)
    STAGE_PA(0);
    STAGE_PB(0);
    asm volatile("s_waitcnt vmcnt(2)\n\ts_barrier" ::: "memory");

#pragma unroll 1
    for (int t = 0; t < NT; ++t) {
        const char* Ab = (const char*)As[t & 1];
        const char* Bb = (const char*)Bs[t & 1];

        // ================= PHASE A: m0,m1 (x 4n) =================
        bf16x8 bfr[4][2];
#pragma unroll
        for (int n = 0; n < 4; ++n) {
            bfr[n][0] = *(const bf16x8*)(Bb + bOff[n] + KB0);
            bfr[n][1] = *(const bf16x8*)(Bb + bOff[n] + KB1);
        }
        bf16x8 af[2][2];
#pragma unroll
        for (int m = 0; m < 2; ++m) {
            af[m][0] = *(const bf16x8*)(Ab + aOff[m] + KB0);
            af[m][1] = *(const bf16x8*)(Ab + aOff[m] + KB1);
        }
        if (t + 1 < NT) STAGE_PA(t + 1);
        asm volatile("s_barrier" ::: "memory");           // reads stay in flight across sync
        asm volatile("s_waitcnt lgkmcnt(0)" ::: "memory");
        __builtin_amdgcn_sched_barrier(0);
        __builtin_amdgcn_s_setprio(1);
#pragma unroll
        for (int k = 0; k < 2; ++k)
#pragma unroll
            for (int m = 0; m < 2; ++m)
#pragma unroll
                for (int n = 0; n < 4; ++n)
                    acc[m][n] = MFMA16(af[m][k], bfr[n][k], acc[m][n]);
        __builtin_amdgcn_s_setprio(0);
        __builtin_amdgcn_sched_barrier(0);
        if (t + 1 < NT)
            asm volatile("s_waitcnt vmcnt(6)\n\ts_barrier" ::: "memory");  // A1ᵗ,A3ᵗ landed
        else
            asm volatile("s_waitcnt vmcnt(0)\n\ts_barrier" ::: "memory");

        // ================= PHASE B: m2,m3 (x 4n) =================
        bf16x8 ag[2][2];
#pragma unroll
        for (int m = 0; m < 2; ++m) {
            ag[m][0] = *(const bf16x8*)(Ab + aOff[2 + m] + KB0);
            ag[m][1] = *(const bf16x8*)(Ab + aOff[2 + m] + KB1);
        }
        if (t + 1 < NT) STAGE_PB(t + 1);
        asm volatile("s_barrier" ::: "memory");
        asm volatile("s_waitcnt lgkmcnt(0)" ::: "memory");
        __builtin_amdgcn_sched_barrier(0);
        __builtin_amdgcn_s_setprio(1);
#pragma unroll
        for (int k = 0; k < 2; ++k)
#pragma unroll
            for (int m = 0; m < 2; ++m)
#pragma unroll
                for (int n = 0; n < 4; ++n)
                    acc[2 + m][n] = MFMA16(ag[m][k], bfr[n][k], acc[2 + m][n]);
        __builtin_amdgcn_s_setprio(0);
        __builtin_amdgcn_sched_barrier(0);
        if (t + 1 < NT)
            asm volatile("s_waitcnt vmcnt(2)\n\ts_barrier" ::: "memory");  // PA(t+1) landed
        else
            asm volatile("s_waitcnt vmcnt(0)\n\ts_barrier" ::: "memory");

        if ((t & 15) == 15) {
            // per-expert epilogue: bias + relu + weighted accumulate (LDS-const only)
            int e = t >> 4;
            float b1v[4];
#pragma unroll
            for (int n = 0; n < 4; ++n)
                b1v[n] = b1Lds[e * 128 + wc * 64 + n * 16 + l15];
#pragma unroll
            for (int m = 0; m < 4; ++m)
#pragma unroll
                for (int j = 0; j < 4; ++j) {
                    int lrow = wr * 64 + m * 16 + kg * 4 + j;
                    float w = wmixLds[lrow * 8 + e];
#pragma unroll
                    for (int n = 0; n < 4; ++n) {
                        float h = fmaxf(acc[m][n][j] + b1v[n], 0.0f);
                        mix[m][n][j] += w * h;
                        acc[m][n][j] = 0.0f;
                    }
                }
        }
    }
#undef KB0
#undef KB1

    // ===== fused head: per-row partial dot over this block's 128 cols =====
    // cols of this lane: bn*128 + wc*64 + n*16 + l15. Reduce over l15 (16 lanes),
    // atomicAdd one partial per (row, wc-wave). bh added once by (bn==0,wc==0).
#pragma unroll
    for (int m = 0; m < 4; ++m)
#pragma unroll
        for (int j = 0; j < 4; ++j) {
            int grow = bm * 128 + wr * 64 + m * 16 + kg * 4 + j;
            int ctx = c[grow];
            const float* whp = Wh + (size_t)ctx * 1024 + bn * 128 + wc * 64;
            float s = 0.0f;
#pragma unroll
            for (int n = 0; n < 4; ++n)
                s += fmaxf(mix[m][n][j], 0.0f) * whp[n * 16 + l15];
            s += __shfl_xor(s, 1);
            s += __shfl_xor(s, 2);
            s += __shfl_xor(s, 4);
            s += __shfl_xor(s, 8);
            if (l15 == 0) {
                if (bn == 0 && wc == 0) s += bh[ctx];
                atomicAdd(q + grow, s);
            }
        }
}

// ---------- host ----------
extern "C" void kernel_launch(void* const* d_in, const int* in_sizes, int n_in,
                              void* d_out, int out_size, void* d_ws, size_t ws_size,
                              hipStream_t stream) {
    const float* state  = (const float*)d_in[0];
    const float* action = (const float*)d_in[1];
    const int*   c      = (const int*)d_in[2];
    const float* W0     = (const float*)d_in[3];
    const float* b0     = (const float*)d_in[4];
    const float* W1     = (const float*)d_in[5];
    const float* b1     = (const float*)d_in[6];
    const float* Wte    = (const float*)d_in[7];
    const float* Wh     = (const float*)d_in[8];
    const float* bh     = (const float*)d_in[9];
    float* q = (float*)d_out;
    int B = in_sizes[2];

    // workspace: 17 MB fixed + H0 full-B 134 MB = 151 MB
    char* p = (char*)d_ws;
    unsigned short* W1T = (unsigned short*)p; p += (size_t)8 * 1024 * 1024 * 2;  // 16 MB
    unsigned short* W0T = (unsigned short*)p; p += (size_t)8 * 1024 * 64 * 2;    // 1 MB
    unsigned short* SA  = (unsigned short*)p; p += (size_t)B * 64 * 2;
    float* wmix         = (float*)p;          p += (size_t)B * 8 * 4;
    unsigned short* H0  = (unsigned short*)p;

    hipMemsetAsync(q, 0, (size_t)B * 4, stream);   // q accumulated via atomics

    k_prep_sa<<<(B + 255) / 256, 256, 0, stream>>>(state, action, c, Wte, SA, wmix, B);
    k_prep_w0t<<<(8 * 1024) / 256, 256, 0, stream>>>(W0, W0T);
    k_prep_w1t<<<dim3(16, 16, 8), 256, 0, stream>>>(W1, W1T);
    k_layer0<<<dim3(B / 128, 8, 8), 256, 0, stream>>>(SA, W0T, b0, H0, B);
    k_fused<<<(B / 128) * 8, 256, 0, stream>>>(H0, W1T, b1, wmix, Wh, bh, c, q, B);
}

// Round 14
// 196.901 us; speedup vs baseline: 2.1547x; 1.0470x over previous
//
#include <hip/hip_runtime.h>
#include <hip/hip_bf16.h>
#include <stdint.h>

// ---------- types ----------
typedef __attribute__((ext_vector_type(8))) __bf16 bf16x8;
typedef __attribute__((ext_vector_type(4))) float f32x4;

__device__ __forceinline__ unsigned short f2b(float f) {
    return __builtin_bit_cast(unsigned short, __float2bfloat16(f));
}

// async global -> LDS, 16B per lane (wave-uniform base + lane*16 dest order)
__device__ __forceinline__ void gload_lds16(const void* g, void* l) {
    __builtin_amdgcn_global_load_lds(
        (__attribute__((address_space(1))) void*)(uintptr_t)g,
        (__attribute__((address_space(3))) void*)l,
        16, 0, 0);
}

#define MFMA16(a, b, c) __builtin_amdgcn_mfma_f32_16x16x32_bf16((a), (b), (c), 0, 0, 0)

// ---------- constants ----------
// B=8192, S=39, A=4, D_IN=43 (pad 64), F=1024, E=8, C=10

// ---------- prep: SA pack + mixture weights ----------
__global__ void k_prep_sa(const float* __restrict__ state, const float* __restrict__ action,
                          const int* __restrict__ c, const float* __restrict__ Wte,
                          unsigned short* __restrict__ SA, float* __restrict__ wmix, int B) {
    int b = blockIdx.x * 256 + threadIdx.x;
    if (b >= B) return;
    unsigned short* row = SA + (size_t)b * 64;
#pragma unroll
    for (int i = 0; i < 39; ++i) row[i] = f2b(state[(size_t)b * 39 + i]);
#pragma unroll
    for (int i = 0; i < 4; ++i) row[39 + i] = f2b(action[(size_t)b * 4 + i]);
#pragma unroll
    for (int i = 43; i < 64; ++i) row[i] = 0;
    int ctx = c[b];
#pragma unroll
    for (int e = 0; e < 8; ++e) wmix[(size_t)b * 8 + e] = Wte[e * 10 + ctx];
}

// ---------- prep: W0 [E,43,1024] f32 -> W0T [E,1024,64] bf16 (n-major, k padded) ----------
__global__ void k_prep_w0t(const float* __restrict__ W0, unsigned short* __restrict__ W0T) {
    int idx = blockIdx.x * 256 + threadIdx.x;   // e*1024 + f
    int e = idx >> 10, f = idx & 1023;
    unsigned short* dst = W0T + (size_t)idx * 64;
#pragma unroll 1
    for (int k = 0; k < 43; ++k) dst[k] = f2b(W0[((size_t)e * 43 + k) * 1024 + f]);
#pragma unroll
    for (int k = 43; k < 64; ++k) dst[k] = 0;
}

// ---------- prep: W1 [E,1024,1024] f32 -> W1T [E,1024(n),1024(k)] bf16 ----------
__global__ void k_prep_w1t(const float* __restrict__ W1, unsigned short* __restrict__ W1T) {
    __shared__ float t[64][65];
    int k0 = blockIdx.x * 64, n0 = blockIdx.y * 64, e = blockIdx.z;
    int tid = threadIdx.x;
    int cl = tid & 63;      // n within tile
    int rg = tid >> 6;      // 0..3
    const float* src = W1 + ((size_t)e * 1024 + k0) * 1024 + n0;
#pragma unroll
    for (int i = 0; i < 16; ++i) {
        int kr = rg * 16 + i;
        t[kr][cl] = src[(size_t)kr * 1024 + cl];
    }
    __syncthreads();
    int nl = tid >> 2, kg = tid & 3;
    unsigned short* dst = W1T + ((size_t)e * 1024 + n0 + nl) * 1024 + k0 + kg * 16;
#pragma unroll
    for (int j = 0; j < 16; ++j) dst[j] = f2b(t[kg * 16 + j][nl]);
}

// ---------- layer 0: H0[e] = relu(SA @ W0T[e]^T + b0[e]), bf16 out (full B) ----------
__global__ __launch_bounds__(256, 2)
void k_layer0(const unsigned short* __restrict__ SA,   // [B,64]
              const unsigned short* __restrict__ W0T,  // [E,1024,64]
              const float* __restrict__ b0,            // [E,1024]
              unsigned short* __restrict__ H0,         // [E,B,1024]
              int Btot) {
    __shared__ unsigned short As[128 * 64];
    __shared__ unsigned short Bs[128 * 64];
    int bm = blockIdx.x, bn = blockIdx.y, e = blockIdx.z;
    int tid = threadIdx.x, lane = tid & 63;
    int wv = tid >> 6, wr = wv >> 1, wc = wv & 1;
    int l15 = lane & 15, kg = lane >> 4;

    const char* Ag = (const char*)(SA + (size_t)(bm * 128) * 64);
    const char* Bg = (const char*)(W0T + ((size_t)e * 1024 + bn * 128) * 64);
#pragma unroll
    for (int it = 0; it < 4; ++it) {
        int off = tid * 16 + it * 4096;   // both tiles are fully contiguous 16KB
        gload_lds16(Ag + off, (char*)As + off);
        gload_lds16(Bg + off, (char*)Bs + off);
    }
    __syncthreads();

    f32x4 acc[4][4];
#pragma unroll
    for (int mi = 0; mi < 4; ++mi)
#pragma unroll
        for (int ni = 0; ni < 4; ++ni) acc[mi][ni] = (f32x4)0.0f;

#pragma unroll
    for (int ks = 0; ks < 2; ++ks) {
        bf16x8 af[4], bv[4];
#pragma unroll
        for (int mi = 0; mi < 4; ++mi)
            af[mi] = *(const bf16x8*)&As[(wr * 64 + mi * 16 + l15) * 64 + ks * 32 + kg * 8];
#pragma unroll
        for (int ni = 0; ni < 4; ++ni)
            bv[ni] = *(const bf16x8*)&Bs[(wc * 64 + ni * 16 + l15) * 64 + ks * 32 + kg * 8];
#pragma unroll
        for (int mi = 0; mi < 4; ++mi)
#pragma unroll
            for (int ni = 0; ni < 4; ++ni)
                acc[mi][ni] = MFMA16(af[mi], bv[ni], acc[mi][ni]);
    }

    float b0v[4];
#pragma unroll
    for (int ni = 0; ni < 4; ++ni)
        b0v[ni] = b0[e * 1024 + bn * 128 + wc * 64 + ni * 16 + l15];
#pragma unroll
    for (int mi = 0; mi < 4; ++mi)
#pragma unroll
        for (int ni = 0; ni < 4; ++ni)
#pragma unroll
            for (int j = 0; j < 4; ++j) {
                int rloc = bm * 128 + wr * 64 + mi * 16 + kg * 4 + j;
                int col = bn * 128 + wc * 64 + ni * 16 + l15;
                float h = fmaxf(acc[mi][ni][j] + b0v[ni], 0.0f);
                H0[((size_t)e * Btot + rloc) * 1024 + col] = f2b(h);
            }
}

// ---------- layer 1 + mixing: 128x128 tile, 2-phase pipeline, 2 blocks/CU ----------
// mixed = relu(sum_e w[b,e]*relu(H0[e] @ W1T[e]^T + b1[e]))
// 256 threads = 4 waves (2M x 2N), per-wave 64x64. BK=64, double-buffered LDS (72KB
// -> 2 blocks/CU; grid 512 = 2/CU). Inter-block overlap absorbs vmcnt/barrier
// stalls. Per K-tile: 2 phases of 16 MFMA; reads+stages issued BEFORE the barrier.
// Stage split {B0..B3,A0,A2} (PA) / {A1,A3} (PB); FIFO gates:
//   after PA: queue [A1(t) A3(t) | 6 of t+1] -> vmcnt(6) certifies PB's data
//   after PB: queue [6 PA(t+1) | 2 PB(t+1)] -> vmcnt(2) certifies PA(t+1)
// Each phase drains lgkmcnt(0) before its trailing barrier -> buffer reuse safe.
// (Best-measured configuration: 152 µs / MfmaUtil 39% in R6.)
__global__ __launch_bounds__(256, 2)
void k_layer1_mix(const unsigned short* __restrict__ H0,   // [E,Btot,1024]
                  const unsigned short* __restrict__ W1T,  // [E,1024(n),1024(k)]
                  const float* __restrict__ b1,            // [E,1024]
                  const float* __restrict__ wmix,          // [B,8]
                  float* __restrict__ mixed,               // [Btot,1024]
                  int Btot) {
    __shared__ unsigned short As[2][128 * 64];   // 2 x 16 KB
    __shared__ unsigned short Bs[2][128 * 64];   // 2 x 16 KB
    __shared__ float wmixLds[128 * 8];           // 4 KB
    __shared__ float b1Lds[8 * 128];             // 4 KB

    int nbm = Btot / 128;
    int wg = blockIdx.x;
    // XCD-coherent mapping (xcd = wg%8): the 8 bn-siblings of a bm get consecutive
    // slots on ONE XCD, so the shared H0 A-panel flows through its L2 once.
    int bm, bn;
    if ((nbm & 7) == 0) {
        int xcd = wg & 7, j = wg >> 3;
        bm = xcd + ((j >> 3) << 3);
        bn = j & 7;
    } else {
        bm = wg >> 3;
        bn = wg & 7;
    }

    int tid = threadIdx.x, lane = tid & 63;
    int wv = tid >> 6;
    int wr = wv >> 1, wc = wv & 1;                // 2M x 2N wave grid
    int l15 = lane & 15, kg = lane >> 4;
    int kg16 = kg * 16;
    int xsw = (l15 & 7) << 4;

    // staging maps: 16B/lane; A and B each 4 issues of 4KB (rows of 128B)
    int tid16 = tid * 16;
    int sSrc[4], sDst[4];
#pragma unroll
    for (int i = 0; i < 4; ++i) {
        int flat = tid16 + i * 4096;
        int row = flat >> 7, colb = flat & 127;
        sDst[i] = flat;
        sSrc[i] = row * 2048 + (colb ^ ((row & 7) << 4));   // inverse-swizzled source
    }

    const char* h0base = (const char*)H0 + (size_t)(bm * 128) * 2048;
    const char* w1base = (const char*)W1T + (size_t)(bn * 128) * 2048;
    size_t eAstride = (size_t)Btot * 2048;

    // fragment read offsets (swizzled; row&7 == l15&7)
    int aOff[4], bOff[4];
#pragma unroll
    for (int m = 0; m < 4; ++m) aOff[m] = (wr * 64 + m * 16 + l15) * 128;
#pragma unroll
    for (int n = 0; n < 4; ++n) bOff[n] = (wc * 64 + n * 16 + l15) * 128;

    // preload wmix + b1 into LDS (keeps the K-loop vmcnt-silent)
    for (int idx = tid; idx < 1024; idx += 256) {
        int r = idx >> 3, e = idx & 7;
        wmixLds[idx] = wmix[(size_t)(bm * 128 + r) * 8 + e];
    }
    for (int idx = tid; idx < 1024; idx += 256)
        b1Lds[idx] = b1[(idx >> 7) * 1024 + bn * 128 + (idx & 127)];
    __syncthreads();   // full drain before the pipeline starts

    f32x4 acc[4][4], mix[4][4];
#pragma unroll
    for (int m = 0; m < 4; ++m)
#pragma unroll
        for (int n = 0; n < 4; ++n) { acc[m][n] = (f32x4)0.0f; mix[m][n] = (f32x4)0.0f; }

    const int NT = 128;   // 8 experts * 16 K-tiles

    auto STAGE_PA = [&](int tt) {   // B full tile + A row-groups 0,2 (phase-A rows)
        int e = tt >> 4;
        int k0b = (tt & 15) << 7;
        const char* Ab = h0base + (size_t)e * eAstride + k0b;
        const char* Bb = w1base + (size_t)e * (1024 * 2048) + k0b;
        char* Ad = (char*)As[tt & 1];
        char* Bd = (char*)Bs[tt & 1];
        gload_lds16(Bb + sSrc[0], Bd + sDst[0]);
        gload_lds16(Bb + sSrc[1], Bd + sDst[1]);
        gload_lds16(Bb + sSrc[2], Bd + sDst[2]);
        gload_lds16(Bb + sSrc[3], Bd + sDst[3]);
        gload_lds16(Ab + sSrc[0], Ad + sDst[0]);
        gload_lds16(Ab + sSrc[2], Ad + sDst[2]);
    };
    auto STAGE_PB = [&](int tt) {   // A row-groups 1,3 (phase-B rows)
        int e = tt >> 4;
        int k0b = (tt & 15) << 7;
        const char* Ab = h0base + (size_t)e * eAstride + k0b;
        char* Ad = (char*)As[tt & 1];
        gload_lds16(Ab + sSrc[1], Ad + sDst[1]);
        gload_lds16(Ab + sSrc[3], Ad + sDst[3]);
    };

#define KB0 ((kg16) ^ xsw)
#define KB1 ((64 + kg16) ^ xsw)

    // prologue: stage tile 0; gate phase-A's 6 loads (2 may still fly)
    STAGE_PA(0);
    STAGE_PB(0);
    asm volatile("s_waitcnt vmcnt(2)\n\ts_barrier" ::: "memory");

#pragma unroll 1
    for (int t = 0; t < NT; ++t) {
        const char* Ab = (const char*)As[t & 1];
        const char* Bb = (const char*)Bs[t & 1];

        // ================= PHASE A: m0,m1 (x 4n) =================
        bf16x8 bfr[4][2];
#pragma unroll
        for (int n = 0; n < 4; ++n) {
            bfr[n][0] = *(const bf16x8*)(Bb + bOff[n] + KB0);
            bfr[n][1] = *(const bf16x8*)(Bb + bOff[n] + KB1);
        }
        bf16x8 af[2][2];
#pragma unroll
        for (int m = 0; m < 2; ++m) {
            af[m][0] = *(const bf16x8*)(Ab + aOff[m] + KB0);
            af[m][1] = *(const bf16x8*)(Ab + aOff[m] + KB1);
        }
        if (t + 1 < NT) STAGE_PA(t + 1);
        asm volatile("s_barrier" ::: "memory");           // reads stay in flight across sync
        asm volatile("s_waitcnt lgkmcnt(0)" ::: "memory");
        __builtin_amdgcn_sched_barrier(0);
        __builtin_amdgcn_s_setprio(1);
#pragma unroll
        for (int k = 0; k < 2; ++k)
#pragma unroll
            for (int m = 0; m < 2; ++m)
#pragma unroll
                for (int n = 0; n < 4; ++n)
                    acc[m][n] = MFMA16(af[m][k], bfr[n][k], acc[m][n]);
        __builtin_amdgcn_s_setprio(0);
        __builtin_amdgcn_sched_barrier(0);
        if (t + 1 < NT)
            asm volatile("s_waitcnt vmcnt(6)\n\ts_barrier" ::: "memory");  // A1(t),A3(t) landed
        else
            asm volatile("s_waitcnt vmcnt(0)\n\ts_barrier" ::: "memory");

        // ================= PHASE B: m2,m3 (x 4n) =================
        bf16x8 ag[2][2];
#pragma unroll
        for (int m = 0; m < 2; ++m) {
            ag[m][0] = *(const bf16x8*)(Ab + aOff[2 + m] + KB0);
            ag[m][1] = *(const bf16x8*)(Ab + aOff[2 + m] + KB1);
        }
        if (t + 1 < NT) STAGE_PB(t + 1);
        asm volatile("s_barrier" ::: "memory");
        asm volatile("s_waitcnt lgkmcnt(0)" ::: "memory");
        __builtin_amdgcn_sched_barrier(0);
        __builtin_amdgcn_s_setprio(1);
#pragma unroll
        for (int k = 0; k < 2; ++k)
#pragma unroll
            for (int m = 0; m < 2; ++m)
#pragma unroll
                for (int n = 0; n < 4; ++n)
                    acc[2 + m][n] = MFMA16(ag[m][k], bfr[n][k], acc[2 + m][n]);
        __builtin_amdgcn_s_setprio(0);
        __builtin_amdgcn_sched_barrier(0);
        if (t + 1 < NT)
            asm volatile("s_waitcnt vmcnt(2)\n\ts_barrier" ::: "memory");  // PA(t+1) landed
        else
            asm volatile("s_waitcnt vmcnt(0)\n\ts_barrier" ::: "memory");

        if ((t & 15) == 15) {
            // per-expert epilogue: bias + relu + weighted accumulate (LDS-const only)
            int e = t >> 4;
            float b1v[4];
#pragma unroll
            for (int n = 0; n < 4; ++n)
                b1v[n] = b1Lds[e * 128 + wc * 64 + n * 16 + l15];
#pragma unroll
            for (int m = 0; m < 4; ++m)
#pragma unroll
                for (int j = 0; j < 4; ++j) {
                    int lrow = wr * 64 + m * 16 + kg * 4 + j;
                    float w = wmixLds[lrow * 8 + e];
#pragma unroll
                    for (int n = 0; n < 4; ++n) {
                        float h = fmaxf(acc[m][n][j] + b1v[n], 0.0f);
                        mix[m][n][j] += w * h;
                        acc[m][n][j] = 0.0f;
                    }
                }
        }
    }
#undef KB0
#undef KB1

    // final relu + store
#pragma unroll
    for (int m = 0; m < 4; ++m)
#pragma unroll
        for (int n = 0; n < 4; ++n)
#pragma unroll
            for (int j = 0; j < 4; ++j) {
                int lrow = wr * 64 + m * 16 + kg * 4 + j;
                int col = bn * 128 + wc * 64 + n * 16 + l15;
                mixed[(size_t)(bm * 128 + lrow) * 1024 + col] = fmaxf(mix[m][n][j], 0.0f);
            }
}

// ---------- head: q[b] = mixed[b,:] . Wh[c[b],:] + bh[c[b]] ----------
__global__ void k_head(const float* __restrict__ mixed, const float* __restrict__ Wh,
                       const float* __restrict__ bh, const int* __restrict__ c,
                       float* __restrict__ q, int Btot) {
    int row = blockIdx.x * 4 + (threadIdx.x >> 6);
    int lane = threadIdx.x & 63;
    if (row >= Btot) return;
    int ctx = c[row];
    const float4* m4 = (const float4*)(mixed + (size_t)row * 1024);
    const float4* w4 = (const float4*)(Wh + (size_t)ctx * 1024);
    float s = 0.0f;
#pragma unroll
    for (int i = 0; i < 4; ++i) {
        float4 a = m4[lane + i * 64];
        float4 b = w4[lane + i * 64];
        s += a.x * b.x + a.y * b.y + a.z * b.z + a.w * b.w;
    }
#pragma unroll
    for (int off = 32; off > 0; off >>= 1) s += __shfl_down(s, off);
    if (lane == 0) q[row] = s + bh[ctx];
}

// ---------- host ----------
extern "C" void kernel_launch(void* const* d_in, const int* in_sizes, int n_in,
                              void* d_out, int out_size, void* d_ws, size_t ws_size,
                              hipStream_t stream) {
    const float* state  = (const float*)d_in[0];
    const float* action = (const float*)d_in[1];
    const int*   c      = (const int*)d_in[2];
    const float* W0     = (const float*)d_in[3];
    const float* b0     = (const float*)d_in[4];
    const float* W1     = (const float*)d_in[5];
    const float* b1     = (const float*)d_in[6];
    const float* Wte    = (const float*)d_in[7];
    const float* Wh     = (const float*)d_in[8];
    const float* bh     = (const float*)d_in[9];
    float* q = (float*)d_out;
    int B = in_sizes[2];

    // workspace: 17 MB fixed + H0 134 MB + mixed f32 33.5 MB = 185 MB
    char* p = (char*)d_ws;
    unsigned short* W1T = (unsigned short*)p; p += (size_t)8 * 1024 * 1024 * 2;  // 16 MB
    unsigned short* W0T = (unsigned short*)p; p += (size_t)8 * 1024 * 64 * 2;    // 1 MB
    unsigned short* SA  = (unsigned short*)p; p += (size_t)B * 64 * 2;
    float* wmix         = (float*)p;          p += (size_t)B * 8 * 4;
    unsigned short* H0  = (unsigned short*)p; p += (size_t)8 * B * 1024 * 2;
    float* mixed        = (float*)p;

    k_prep_sa<<<(B + 255) / 256, 256, 0, stream>>>(state, action, c, Wte, SA, wmix, B);
    k_prep_w0t<<<(8 * 1024) / 256, 256, 0, stream>>>(W0, W0T);
    k_prep_w1t<<<dim3(16, 16, 8), 256, 0, stream>>>(W1, W1T);
    k_layer0<<<dim3(B / 128, 8, 8), 256, 0, stream>>>(SA, W0T, b0, H0, B);
    k_layer1_mix<<<(B / 128) * 8, 256, 0, stream>>>(H0, W1T, b1, wmix, mixed, B);
    k_head<<<(B + 3) / 4, 256, 0, stream>>>(mixed, Wh, bh, c, q, B);
}